// Round 10
// baseline (330.825 us; speedup 1.0000x reference)
//
#include <hip/hip_runtime.h>

typedef _Float16 f16;
typedef _Float16 half8 __attribute__((ext_vector_type(8)));
typedef _Float16 half4 __attribute__((ext_vector_type(4)));
typedef float f32x4 __attribute__((ext_vector_type(4)));

#define B_SZ 512
#define NQ   128
#define CH   512
#define NH   8
#define DH   64
#define MTOK (B_SZ*NQ)   // 65536 tokens
#define KD   512

#define MFMA16(a,b,c) __builtin_amdgcn_mfma_f32_16x16x32_f16((a),(b),(c),0,0,0)

// global -> LDS direct DMA, 16B per lane. LDS dest is wave-uniform base + lane*16.
#define GLDS16(g,l) __builtin_amdgcn_global_load_lds( \
    (__attribute__((address_space(1))) void*)(g), \
    (__attribute__((address_space(3))) void*)(l), 16, 0, 0)

// ---------------- kernel 0: W^T fp32 -> fp16 only (x-pass fused into k_qkv) ----------------
__global__ __launch_bounds__(256) void k_prep(
    const float* __restrict__ Wq, const float* __restrict__ Wk,
    const float* __restrict__ Wv, const float* __restrict__ Wo,
    f16* __restrict__ wt) {
  const int bid = blockIdx.x;   // 512 blocks, 4 wt rows each
  for (int e = threadIdx.x; e < 2048; e += 256) {
    const int n = bid * 4 + (e >> 9);
    const int k = e & 511;
    const float* W = (n < 512) ? Wq : (n < 1024) ? Wk : (n < 1536) ? Wv : Wo;
    wt[n * 512 + k] = (f16)W[k * 512 + (n & 511)];
  }
}

// ===== shared pieces of the BK=64 swizzled core (see R9 comments) =====
// LDS [128][64] f16; swizzle: LDS(row, slot) holds global (row, slot^(row&7)),
// slot = 16B chunk. Staging dest linear (lane*16B); source col pre-permuted.
// Read: row&7 == ln&7 -> slot' = (ks*4+g)^(ln&7): 2-way banks (free).
__device__ __forceinline__ int stage_src_off() {
  const int lane = threadIdx.x & 63, w = threadIdx.x >> 6;
  return (w * 8 + (lane >> 3)) * KD + (((lane & 7) ^ (lane >> 3)) << 3);
}

#define CMP_BODY(la, lb) do { \
  half8 af[4], bf[4]; \
  _Pragma("unroll") for (int ks = 0; ks < 2; ++ks) { \
    const int sx = ks ? sx1 : sx0; \
    _Pragma("unroll") for (int m = 0; m < 4; ++m) \
      af[m] = *(const half8*)((la) + roA0 + m * 1024 + sx); \
    _Pragma("unroll") for (int n = 0; n < 4; ++n) \
      bf[n] = *(const half8*)((lb) + roB0 + n * 1024 + sx); \
    __builtin_amdgcn_s_setprio(1); \
    _Pragma("unroll") for (int m = 0; m < 4; ++m) \
      _Pragma("unroll") for (int n = 0; n < 4; ++n) \
        acc[m][n] = MFMA16(af[m], bf[n], acc[m][n]); \
    __builtin_amdgcn_s_setprio(0); } } while (0)

// ---------------- kernel 1: fused cvt + QKV projection GEMM ----------------
// A staged from fp32 x: reg-load (issued one step early) -> cvt -> ds_write.
// B staged via GLDS from fp16 wt. Counted waits; A-prefetch never drained mid-loop.
// Per step: [GLDS B(t)] vmcnt(4)->A(t) regs ready; cvt+ds_write A(t); issue A(t+1);
// vmcnt(8) lgkmcnt(0); barrier; MFMA(t); raw barrier (WAR).
__global__ __launch_bounds__(256, 3) void k_qkv(
    const float* __restrict__ x, const f16* __restrict__ Bw,
    const float* __restrict__ bq, const float* __restrict__ bk,
    const float* __restrict__ bv,
    f16* __restrict__ qb, f16* __restrict__ kb, f16* __restrict__ vb) {
  __shared__ f16 la[128 * 64];
  __shared__ f16 lb[128 * 64];
  const int tid = threadIdx.x;
  const int w = tid >> 6, lane = tid & 63;
  const int ln = lane & 15, g = lane >> 4;
  const int wr = w >> 1, wc = w & 1;
  const int s = blockIdx.x >> 3;
  const int ml = s / 12;
  const int ntile = s - ml * 12;
  const int mtile = (blockIdx.x & 7) * 64 + ml;   // xcd-local A panels

  const int w512 = w * 512;
  const int roA0 = (wr * 64 + ln) * 64;
  const int roB0 = (wc * 64 + ln) * 64;
  const int sx0 = ((0 + g) ^ (ln & 7)) * 8;
  const int sx1 = ((4 + g) ^ (ln & 7)) * 8;

  // A source (fp32): row = mtile*128 + i*32 + w*8 + (lane>>3), col pre-permuted
  const float* gAx = x + (size_t)(mtile * 128 + w * 8 + (lane >> 3)) * KD +
                     (((lane & 7) ^ (lane >> 3)) << 3);
  const f16* gBs = Bw + ntile * 128 * KD + stage_src_off();

  f32x4 ar[4][2];
#define ALOAD(K0) do { _Pragma("unroll") \
  for (int i = 0; i < 4; ++i) { \
    ar[i][0] = *(const f32x4*)(gAx + i * 32 * KD + (K0)); \
    ar[i][1] = *(const f32x4*)(gAx + i * 32 * KD + (K0) + 4); } } while (0)
#define AWRITE() do { _Pragma("unroll") \
  for (int i = 0; i < 4; ++i) { \
    half8 h; \
    _Pragma("unroll") for (int j = 0; j < 4; ++j) { \
      h[j] = (f16)ar[i][0][j]; h[4 + j] = (f16)ar[i][1][j]; } \
    *(half8*)(la + i * 2048 + w512 + lane * 8) = h; } } while (0)
#define BSTAGE(K0) do { _Pragma("unroll") \
  for (int i = 0; i < 4; ++i) \
    GLDS16(gBs + i * 32 * KD + (K0), lb + i * 2048 + w512); } while (0)

  f32x4 acc[4][4] = {};
  ALOAD(0);                      // prologue: A(0) in flight

#pragma unroll 1
  for (int t = 0; t < 7; ++t) {
    const int k0 = t * 64;
    BSTAGE(k0);                                            // 4 GLDS (newest)
    asm volatile("s_waitcnt vmcnt(4)" ::: "memory");       // A(t) regs landed
    AWRITE();                                              // la <- cvt(A(t))
    ALOAD(k0 + 64);                                        // A(t+1) in flight
    asm volatile("s_waitcnt vmcnt(8) lgkmcnt(0)" ::: "memory");  // B(t)+writes done
    __builtin_amdgcn_s_barrier();
    CMP_BODY(la, lb);
    __builtin_amdgcn_s_barrier();                          // WAR: reads done
  }
  // t = 7
  BSTAGE(448);
  asm volatile("s_waitcnt vmcnt(4)" ::: "memory");
  AWRITE();
  asm volatile("s_waitcnt vmcnt(0) lgkmcnt(0)" ::: "memory");
  __builtin_amdgcn_s_barrier();
  CMP_BODY(la, lb);
#undef ALOAD
#undef AWRITE
#undef BSTAGE

  const int b = mtile;  // 128 rows per tile == one batch
  const int colbase = ntile * 128 + wc * 64;
#pragma unroll
  for (int m = 0; m < 4; ++m) {
    const int nn0 = wr * 64 + m * 16 + g * 4;  // token row in batch (reg 0)
#pragma unroll
    for (int n = 0; n < 4; ++n) {
      const int col = colbase + n * 16 + ln;
      const int which = col >> 9;      // 0=Q 1=K 2=V (uniform per n)
      const int c = col & 511;
      const int h = c >> 6, d = c & 63;
      const float bias = (which == 0) ? bq[c] : (which == 1) ? bk[c] : bv[c];
      if (which < 2) {
        f16* dst = ((which == 0) ? qb : kb) + ((b * NH + h) * NQ + nn0) * DH + d;
#pragma unroll
        for (int r = 0; r < 4; ++r)
          dst[r * DH] = (f16)(acc[m][n][r] + bias);
      } else {
        half4 v4;
#pragma unroll
        for (int r = 0; r < 4; ++r)
          v4[r] = (f16)(acc[m][n][r] + bias);
        *(half4*)(vb + ((b * NH + h) * DH + d) * NQ + nn0) = v4;  // V^T
      }
    }
  }
}

// ---------------- kernel 2: causal attention, one block per (b,h) ----------------
__global__ __launch_bounds__(256, 2) void k_attn(
    const f16* __restrict__ qbuf, const f16* __restrict__ kbuf,
    const f16* __restrict__ vbuf, f16* __restrict__ ao) {
  __shared__ f16 kl[128 * 72];   // K [key][d], padded stride 72
  __shared__ f16 vl[64 * 136];   // V^T [d][key], padded stride 136
  __shared__ f16 pl[128 * 136];  // P [q][key], padded stride 136; later O bounce
  const int bh = blockIdx.x;
  const f16* Qp = qbuf + bh * (NQ * DH);
  const f16* Kp = kbuf + bh * (NQ * DH);
  const f16* Vp = vbuf + bh * (DH * NQ);
  const int tid = threadIdx.x;
  const int w = tid >> 6, lane = tid & 63;
  const int ln = lane & 15, g = lane >> 4;

#pragma unroll
  for (int i = 0; i < 4; ++i) {
    const int e = i * 2048 + tid * 8;
    *(half8*)(kl + (e >> 6) * 72 + (e & 63)) = *(const half8*)(Kp + e);
  }
#pragma unroll
  for (int i = 0; i < 4; ++i) {
    const int e = i * 2048 + tid * 8;
    *(half8*)(vl + (e >> 7) * 136 + (e & 127)) = *(const half8*)(Vp + e);
  }
  half8 qf[2][2];
#pragma unroll
  for (int m = 0; m < 2; ++m)
#pragma unroll
    for (int ks = 0; ks < 2; ++ks)
      qf[m][ks] = *(const half8*)(Qp + (w * 32 + m * 16 + ln) * DH + ks * 32 + g * 8);
  __syncthreads();

  f32x4 s[2][8] = {};
#pragma unroll
  for (int ks = 0; ks < 2; ++ks)
#pragma unroll
    for (int n = 0; n < 8; ++n) {
      half8 kf = *(const half8*)(kl + (n * 16 + ln) * 72 + ks * 32 + g * 8);
      s[0][n] = MFMA16(qf[0][ks], kf, s[0][n]);
      s[1][n] = MFMA16(qf[1][ks], kf, s[1][n]);
    }

  float inv[2][4];
#pragma unroll
  for (int m = 0; m < 2; ++m) {
#pragma unroll
    for (int r = 0; r < 4; ++r) {
      const int q = w * 32 + m * 16 + g * 4 + r;
      float z[8];
      float rm = -1e30f;
#pragma unroll
      for (int n = 0; n < 8; ++n) {
        const int col = n * 16 + ln;
        float zz = s[m][n][r] * 0.125f + ((col > q) ? -12500.0f : 0.0f);
        z[n] = zz;
        rm = fmaxf(rm, zz);
      }
      rm = fmaxf(rm, __shfl_xor(rm, 1));
      rm = fmaxf(rm, __shfl_xor(rm, 2));
      rm = fmaxf(rm, __shfl_xor(rm, 4));
      rm = fmaxf(rm, __shfl_xor(rm, 8));
      float rs = 0.f;
#pragma unroll
      for (int n = 0; n < 8; ++n) {
        const float p = __expf(z[n] - rm);   // masked cols -> exact 0
        rs += p;
        pl[q * 136 + n * 16 + ln] = (f16)p;  // unnormalized P
      }
      rs += __shfl_xor(rs, 1);
      rs += __shfl_xor(rs, 2);
      rs += __shfl_xor(rs, 4);
      rs += __shfl_xor(rs, 8);
      inv[m][r] = 1.0f / rs;
    }
  }

  f32x4 o[2][4] = {};
#pragma unroll
  for (int ks = 0; ks < 4; ++ks) {
    half8 pf0 = *(const half8*)(pl + (w * 32 + ln) * 136 + ks * 32 + g * 8);
    half8 pf1 = *(const half8*)(pl + (w * 32 + 16 + ln) * 136 + ks * 32 + g * 8);
#pragma unroll
    for (int n = 0; n < 4; ++n) {
      half8 vf = *(const half8*)(vl + (n * 16 + ln) * 136 + ks * 32 + g * 8);
      o[0][n] = MFMA16(pf0, vf, o[0][n]);
      o[1][n] = MFMA16(pf1, vf, o[1][n]);
    }
  }

  // O -> pl bounce (pl dead after PV), then coalesced 128B half8 stores
  __syncthreads();
#pragma unroll
  for (int m = 0; m < 2; ++m)
#pragma unroll
    for (int n = 0; n < 4; ++n)
#pragma unroll
      for (int r = 0; r < 4; ++r)
        pl[(w * 32 + m * 16 + g * 4 + r) * 136 + n * 16 + ln] =
            (f16)(o[m][n][r] * inv[m][r]);
  __syncthreads();
  const int b = bh >> 3, h = bh & 7;
  f16* dst = ao + (size_t)(b * NQ) * CH + h * DH;
  const int lr = lane >> 3, lc = lane & 7;   // 8 rows x (8 lanes of 16B)
#pragma unroll
  for (int p = 0; p < 4; ++p) {
    const int q = w * 32 + p * 8 + lr;
    half8 v = *(const half8*)(pl + q * 136 + lc * 8);
    *(half8*)(dst + (size_t)q * CH + lc * 8) = v;
  }
}

// ---------------- kernel 3: output projection GEMM (R9 BK=64 GLDS core) ----------------
__global__ __launch_bounds__(256, 4) void k_out(
    const f16* __restrict__ A, const f16* __restrict__ Bw,
    const float* __restrict__ bo, float* __restrict__ out) {
  __shared__ f16 la[128 * 64];
  __shared__ f16 lb[128 * 64];
  const int tid = threadIdx.x;
  const int w = tid >> 6, lane = tid & 63;
  const int ln = lane & 15, g = lane >> 4;
  const int wr = w >> 1, wc = w & 1;
  const int s = blockIdx.x >> 3;
  const int ml = s >> 2;
  const int ntile = s & 3;
  const int mtile = (blockIdx.x & 7) * 64 + ml;

  const int w512 = w * 512;
  const int roA0 = (wr * 64 + ln) * 64;
  const int roB0 = (wc * 64 + ln) * 64;
  const int sx0 = ((0 + g) ^ (ln & 7)) * 8;
  const int sx1 = ((4 + g) ^ (ln & 7)) * 8;

  const int so = stage_src_off();
  const f16* gA = A + mtile * 128 * KD + so;
  const f16* gB = Bw + ntile * 128 * KD + so;

  f32x4 acc[4][4] = {};
#pragma unroll 1
  for (int kt = 0; kt < 8; ++kt) {
    const int k0 = kt * 64;
#pragma unroll
    for (int i = 0; i < 4; ++i) {
      GLDS16(gA + i * 32 * KD + k0, la + i * 2048 + w512);
      GLDS16(gB + i * 32 * KD + k0, lb + i * 2048 + w512);
    }
    __syncthreads();
    CMP_BODY(la, lb);
    __syncthreads();
  }

  const int colbase = ntile * 128 + wc * 64;
#pragma unroll
  for (int m = 0; m < 4; ++m) {
    const int tok0 = mtile * 128 + wr * 64 + m * 16 + g * 4;
#pragma unroll
    for (int n = 0; n < 4; ++n) {
      const int col = colbase + n * 16 + ln;
      const float bias = bo[col];
      float* dst = out + (size_t)tok0 * CH + col;
#pragma unroll
      for (int r = 0; r < 4; ++r)
        dst[r * CH] = acc[m][n][r] + bias;
    }
  }
}

extern "C" void kernel_launch(void* const* d_in, const int* in_sizes, int n_in,
                              void* d_out, int out_size, void* d_ws, size_t ws_size,
                              hipStream_t stream) {
  (void)in_sizes; (void)n_in; (void)out_size; (void)ws_size;
  const float* x  = (const float*)d_in[0];
  const float* Wq = (const float*)d_in[1];
  const float* bq = (const float*)d_in[2];
  const float* Wk = (const float*)d_in[3];
  const float* bk = (const float*)d_in[4];
  const float* Wv = (const float*)d_in[5];
  const float* bv = (const float*)d_in[6];
  const float* Wo = (const float*)d_in[7];
  const float* bo = (const float*)d_in[8];
  float* out = (float*)d_out;

  char* ws = (char*)d_ws;
  const size_t SZ = (size_t)MTOK * KD * sizeof(f16);  // 64 MB
  f16* ao = (f16*)(ws);                // attn out [tok][ch]
  f16* qb = (f16*)(ws + SZ);           // Q [b][h][n][d]
  f16* kb = (f16*)(ws + 2 * SZ);       // K [b][h][n][d]
  f16* vb = (f16*)(ws + 3 * SZ);       // V^T [b][h][d][n]
  f16* wt = (f16*)(ws + 4 * SZ);       // W^T fp16, 2048x512

  k_prep<<<512, 256, 0, stream>>>(Wq, Wk, Wv, Wo, wt);
  k_qkv<<<6144, 256, 0, stream>>>(x, wt, bq, bk, bv, qb, kb, vb);
  k_attn<<<4096, 256, 0, stream>>>(qb, kb, vb, ao);
  k_out<<<2048, 256, 0, stream>>>(ao, wt + 1536 * KD, bo, out);
}

// Round 11
// 307.574 us; speedup vs baseline: 1.0756x; 1.0756x over previous
//
#include <hip/hip_runtime.h>

typedef _Float16 f16;
typedef _Float16 half8 __attribute__((ext_vector_type(8)));
typedef _Float16 half4 __attribute__((ext_vector_type(4)));
typedef float f32x4 __attribute__((ext_vector_type(4)));

#define B_SZ 512
#define NQ   128
#define CH   512
#define NH   8
#define DH   64
#define MTOK (B_SZ*NQ)   // 65536 tokens
#define KD   512

#define MFMA16(a,b,c) __builtin_amdgcn_mfma_f32_16x16x32_f16((a),(b),(c),0,0,0)

// global -> LDS direct DMA, 16B per lane. LDS dest is wave-uniform base + lane*16.
#define GLDS16(g,l) __builtin_amdgcn_global_load_lds( \
    (__attribute__((address_space(1))) void*)(g), \
    (__attribute__((address_space(3))) void*)(l), 16, 0, 0)

// ---------------- kernel 0: x fp32->fp16  +  W^T fp32->fp16, one launch ----------------
__global__ __launch_bounds__(256) void k_prep(
    const float* __restrict__ x,
    const float* __restrict__ Wq, const float* __restrict__ Wk,
    const float* __restrict__ Wv, const float* __restrict__ Wo,
    f16* __restrict__ xb, f16* __restrict__ wt) {
  const int bid = blockIdx.x;
  if (bid < 512) {
    for (int e = threadIdx.x; e < 2048; e += 256) {
      const int n = bid * 4 + (e >> 9);
      const int k = e & 511;
      const float* W = (n < 512) ? Wq : (n < 1024) ? Wk : (n < 1536) ? Wv : Wo;
      wt[n * 512 + k] = (f16)W[k * 512 + (n & 511)];
    }
  } else {
    const int n8 = MTOK * KD / 8;
    int i = (bid - 512) * 256 + threadIdx.x;
    const int stride = 2048 * 256;
    for (; i < n8; i += stride) {
      f32x4 a = ((const f32x4*)x)[2 * i];
      f32x4 b = ((const f32x4*)x)[2 * i + 1];
      half8 h;
      h[0] = (f16)a[0]; h[1] = (f16)a[1]; h[2] = (f16)a[2]; h[3] = (f16)a[3];
      h[4] = (f16)b[0]; h[5] = (f16)b[1]; h[6] = (f16)b[2]; h[7] = (f16)b[3];
      ((half8*)xb)[i] = h;
    }
  }
}

// ========== 128x128 GEMM core, BK=64, single-buffer (8 K-steps), R9-proven ==========
// LDS [128][64] f16; swizzle: LDS(row, slot) holds global (row, slot^(row&7)),
// slot = 16B chunk. Staging dest linear (lane*16B); source col pre-permuted.
// Read: row&7 == ln&7 -> slot' = (ks*4+g)^(ln&7): 2-way banks (free).
// SW=false: acc = mfma(a,b) -> D[tok=g*4+r][other=ln]
// SW=true : acc = mfma(b,a) -> D[chan=g*4+r][tok=ln]  (contiguous-channel epilogue)
__device__ __forceinline__ int stage_src_off() {
  const int lane = threadIdx.x & 63, w = threadIdx.x >> 6;
  return (w * 8 + (lane >> 3)) * KD + (((lane & 7) ^ (lane >> 3)) << 3);
}

template<bool SW>
__device__ __forceinline__ void gemm128_bk64(
    const f16* __restrict__ gA,   // per-thread staging addr (pre-swizzled source)
    const f16* __restrict__ gB,
    f16* la, f16* lb, f32x4 (&acc)[4][4]) {
  const int tid = threadIdx.x;
  const int w = tid >> 6, lane = tid & 63;
  const int ln = lane & 15, g = lane >> 4;
  const int wr = w >> 1, wc = w & 1;

  const int ldst = w * 512;
  const int roA0 = (wr * 64 + ln) * 64;
  const int roB0 = (wc * 64 + ln) * 64;
  const int sx0 = ((0 + g) ^ (ln & 7)) * 8;
  const int sx1 = ((4 + g) ^ (ln & 7)) * 8;

#pragma unroll 1
  for (int kt = 0; kt < 8; ++kt) {
    const int k0 = kt * 64;
#pragma unroll
    for (int i = 0; i < 4; ++i) {
      GLDS16(gA + i * 32 * KD + k0, la + i * 2048 + ldst);
      GLDS16(gB + i * 32 * KD + k0, lb + i * 2048 + ldst);
    }
    __syncthreads();   // compiler drains vmcnt before s_barrier
    half8 af[4], bf[4];
#pragma unroll
    for (int ks = 0; ks < 2; ++ks) {
      const int sx = ks ? sx1 : sx0;
#pragma unroll
      for (int m = 0; m < 4; ++m)
        af[m] = *(const half8*)(la + roA0 + m * 1024 + sx);
#pragma unroll
      for (int n = 0; n < 4; ++n)
        bf[n] = *(const half8*)(lb + roB0 + n * 1024 + sx);
      __builtin_amdgcn_s_setprio(1);
#pragma unroll
      for (int m = 0; m < 4; ++m)
#pragma unroll
        for (int n = 0; n < 4; ++n)
          acc[m][n] = SW ? MFMA16(bf[n], af[m], acc[m][n])
                         : MFMA16(af[m], bf[n], acc[m][n]);
      __builtin_amdgcn_s_setprio(0);
    }
    __syncthreads();
  }
}

// ---------------- kernel 1: fused QKV projection GEMM ----------------
// XCD mapping: xcd = bid&7 owns mtiles [xcd*64, xcd*64+64); the 12 ntile-blocks of an
// mtile run on one XCD -> A panel fetched once into that XCD's L2.
// which = ntile>>2 is BLOCK-uniform: Q/K use swapped orientation (contiguous half4
// channel stores), V uses normal orientation (contiguous half4 token stores in V^T).
__global__ __launch_bounds__(256, 4) void k_qkv(
    const f16* __restrict__ A, const f16* __restrict__ Bw,
    const float* __restrict__ bq, const float* __restrict__ bk,
    const float* __restrict__ bv,
    f16* __restrict__ qb, f16* __restrict__ kb, f16* __restrict__ vb) {
  __shared__ f16 la[128 * 64];
  __shared__ f16 lb[128 * 64];
  const int tid = threadIdx.x;
  const int w = tid >> 6, lane = tid & 63;
  const int ln = lane & 15, g = lane >> 4;
  const int wr = w >> 1, wc = w & 1;
  const int s = blockIdx.x >> 3;
  const int ml = s / 12;
  const int ntile = s - ml * 12;
  const int mtile = (blockIdx.x & 7) * 64 + ml;

  const int so = stage_src_off();
  const f16* gA = A + mtile * 128 * KD + so;
  const f16* gB = Bw + ntile * 128 * KD + so;

  f32x4 acc[4][4] = {};
  const int b = mtile;  // 128 rows per tile == one batch
  const int colbase = ntile * 128 + wc * 64;

  if (ntile < 8) {   // ---- Q or K: swapped orientation ----
    gemm128_bk64<true>(gA, gB, la, lb, acc);
    const float* bias = (ntile < 4) ? bq : bk;
    f16* dstb = (ntile < 4) ? qb : kb;
#pragma unroll
    for (int n = 0; n < 4; ++n) {
      const int c = (colbase + n * 16 + g * 4) & 511;
      const int h = c >> 6, d = c & 63;
      const f32x4 b4 = *(const f32x4*)(bias + c);
#pragma unroll
      for (int m = 0; m < 4; ++m) {
        const int tok = wr * 64 + m * 16 + ln;   // token row within batch
        half4 o;
#pragma unroll
        for (int r = 0; r < 4; ++r) o[r] = (f16)(acc[m][n][r] + b4[r]);
        *(half4*)(dstb + ((b * NH + h) * NQ + tok) * DH + d) = o;
      }
    }
  } else {           // ---- V: normal orientation, V^T out ----
    gemm128_bk64<false>(gA, gB, la, lb, acc);
#pragma unroll
    for (int n = 0; n < 4; ++n) {
      const int c = (colbase + n * 16 + ln) & 511;
      const int h = c >> 6, d = c & 63;
      const float bias = bv[c];
#pragma unroll
      for (int m = 0; m < 4; ++m) {
        const int nn0 = wr * 64 + m * 16 + g * 4;
        half4 v4;
#pragma unroll
        for (int r = 0; r < 4; ++r) v4[r] = (f16)(acc[m][n][r] + bias);
        *(half4*)(vb + ((b * NH + h) * DH + d) * NQ + nn0) = v4;  // V^T
      }
    }
  }
}

// ---------------- kernel 2: causal attention, one block per (b,h) ----------------
__global__ __launch_bounds__(256, 2) void k_attn(
    const f16* __restrict__ qbuf, const f16* __restrict__ kbuf,
    const f16* __restrict__ vbuf, f16* __restrict__ ao) {
  __shared__ f16 kl[128 * 72];   // K [key][d], padded stride 72
  __shared__ f16 vl[64 * 136];   // V^T [d][key], padded stride 136
  __shared__ f16 pl[128 * 136];  // P [q][key], padded stride 136; later O bounce
  const int bh = blockIdx.x;
  const f16* Qp = qbuf + bh * (NQ * DH);
  const f16* Kp = kbuf + bh * (NQ * DH);
  const f16* Vp = vbuf + bh * (DH * NQ);
  const int tid = threadIdx.x;
  const int w = tid >> 6, lane = tid & 63;
  const int ln = lane & 15, g = lane >> 4;

#pragma unroll
  for (int i = 0; i < 4; ++i) {
    const int e = i * 2048 + tid * 8;
    *(half8*)(kl + (e >> 6) * 72 + (e & 63)) = *(const half8*)(Kp + e);
  }
#pragma unroll
  for (int i = 0; i < 4; ++i) {
    const int e = i * 2048 + tid * 8;
    *(half8*)(vl + (e >> 7) * 136 + (e & 127)) = *(const half8*)(Vp + e);
  }
  half8 qf[2][2];
#pragma unroll
  for (int m = 0; m < 2; ++m)
#pragma unroll
    for (int ks = 0; ks < 2; ++ks)
      qf[m][ks] = *(const half8*)(Qp + (w * 32 + m * 16 + ln) * DH + ks * 32 + g * 8);
  __syncthreads();

  f32x4 s[2][8] = {};
#pragma unroll
  for (int ks = 0; ks < 2; ++ks)
#pragma unroll
    for (int n = 0; n < 8; ++n) {
      half8 kf = *(const half8*)(kl + (n * 16 + ln) * 72 + ks * 32 + g * 8);
      s[0][n] = MFMA16(qf[0][ks], kf, s[0][n]);
      s[1][n] = MFMA16(qf[1][ks], kf, s[1][n]);
    }

  float inv[2][4];
#pragma unroll
  for (int m = 0; m < 2; ++m) {
#pragma unroll
    for (int r = 0; r < 4; ++r) {
      const int q = w * 32 + m * 16 + g * 4 + r;
      float z[8];
      float rm = -1e30f;
#pragma unroll
      for (int n = 0; n < 8; ++n) {
        const int col = n * 16 + ln;
        float zz = s[m][n][r] * 0.125f + ((col > q) ? -12500.0f : 0.0f);
        z[n] = zz;
        rm = fmaxf(rm, zz);
      }
      rm = fmaxf(rm, __shfl_xor(rm, 1));
      rm = fmaxf(rm, __shfl_xor(rm, 2));
      rm = fmaxf(rm, __shfl_xor(rm, 4));
      rm = fmaxf(rm, __shfl_xor(rm, 8));
      float rs = 0.f;
#pragma unroll
      for (int n = 0; n < 8; ++n) {
        const float p = __expf(z[n] - rm);   // masked cols -> exact 0
        rs += p;
        pl[q * 136 + n * 16 + ln] = (f16)p;  // unnormalized P
      }
      rs += __shfl_xor(rs, 1);
      rs += __shfl_xor(rs, 2);
      rs += __shfl_xor(rs, 4);
      rs += __shfl_xor(rs, 8);
      inv[m][r] = 1.0f / rs;
    }
  }

  f32x4 o[2][4] = {};
#pragma unroll
  for (int ks = 0; ks < 4; ++ks) {
    half8 pf0 = *(const half8*)(pl + (w * 32 + ln) * 136 + ks * 32 + g * 8);
    half8 pf1 = *(const half8*)(pl + (w * 32 + 16 + ln) * 136 + ks * 32 + g * 8);
#pragma unroll
    for (int n = 0; n < 4; ++n) {
      half8 vf = *(const half8*)(vl + (n * 16 + ln) * 136 + ks * 32 + g * 8);
      o[0][n] = MFMA16(pf0, vf, o[0][n]);
      o[1][n] = MFMA16(pf1, vf, o[1][n]);
    }
  }

  // O -> pl bounce (pl dead after PV), then coalesced 128B half8 stores
  __syncthreads();
#pragma unroll
  for (int m = 0; m < 2; ++m)
#pragma unroll
    for (int n = 0; n < 4; ++n)
#pragma unroll
      for (int r = 0; r < 4; ++r)
        pl[(w * 32 + m * 16 + g * 4 + r) * 136 + n * 16 + ln] =
            (f16)(o[m][n][r] * inv[m][r]);
  __syncthreads();
  const int b = bh >> 3, h = bh & 7;
  f16* dst = ao + (size_t)(b * NQ) * CH + h * DH;
  const int lr = lane >> 3, lc = lane & 7;   // 8 rows x (8 lanes of 16B)
#pragma unroll
  for (int p = 0; p < 4; ++p) {
    const int q = w * 32 + p * 8 + lr;
    half8 v = *(const half8*)(pl + q * 136 + lc * 8);
    *(half8*)(dst + (size_t)q * CH + lc * 8) = v;
  }
}

// ---------------- kernel 3: output projection GEMM (BK=64, swapped epilogue) ----------------
__global__ __launch_bounds__(256, 4) void k_out(
    const f16* __restrict__ A, const f16* __restrict__ Bw,
    const float* __restrict__ bo, float* __restrict__ out) {
  __shared__ f16 la[128 * 64];
  __shared__ f16 lb[128 * 64];
  const int tid = threadIdx.x;
  const int w = tid >> 6, lane = tid & 63;
  const int ln = lane & 15, g = lane >> 4;
  const int wr = w >> 1, wc = w & 1;
  const int s = blockIdx.x >> 3;
  const int ml = s >> 2;
  const int ntile = s & 3;
  const int mtile = (blockIdx.x & 7) * 64 + ml;

  const int so = stage_src_off();
  const f16* gA = A + mtile * 128 * KD + so;
  const f16* gB = Bw + ntile * 128 * KD + so;

  f32x4 acc[4][4] = {};
  gemm128_bk64<true>(gA, gB, la, lb, acc);   // D[chan=g*4+r][tok=ln]

  const int colbase = ntile * 128 + wc * 64;
#pragma unroll
  for (int n = 0; n < 4; ++n) {
    const int col = colbase + n * 16 + g * 4;
    const f32x4 b4 = *(const f32x4*)(bo + col);
#pragma unroll
    for (int m = 0; m < 4; ++m) {
      const int tok = mtile * 128 + wr * 64 + m * 16 + ln;
      *(f32x4*)(out + (size_t)tok * CH + col) = acc[m][n] + b4;
    }
  }
}

extern "C" void kernel_launch(void* const* d_in, const int* in_sizes, int n_in,
                              void* d_out, int out_size, void* d_ws, size_t ws_size,
                              hipStream_t stream) {
  (void)in_sizes; (void)n_in; (void)out_size; (void)ws_size;
  const float* x  = (const float*)d_in[0];
  const float* Wq = (const float*)d_in[1];
  const float* bq = (const float*)d_in[2];
  const float* Wk = (const float*)d_in[3];
  const float* bk = (const float*)d_in[4];
  const float* Wv = (const float*)d_in[5];
  const float* bv = (const float*)d_in[6];
  const float* Wo = (const float*)d_in[7];
  const float* bo = (const float*)d_in[8];
  float* out = (float*)d_out;

  char* ws = (char*)d_ws;
  const size_t SZ = (size_t)MTOK * KD * sizeof(f16);  // 64 MB
  f16* xb = (f16*)(ws);                // x in fp16
  f16* qb = (f16*)(ws + SZ);           // Q [b][h][n][d]
  f16* kb = (f16*)(ws + 2 * SZ);       // K [b][h][n][d]
  f16* vb = (f16*)(ws + 3 * SZ);       // V^T [b][h][d][n]
  f16* wt = (f16*)(ws + 4 * SZ);       // W^T fp16, 2048x512
  f16* ao = xb;                        // attn out aliases xb (xb dead by then)

  k_prep<<<2560, 256, 0, stream>>>(x, Wq, Wk, Wv, Wo, xb, wt);
  k_qkv<<<6144, 256, 0, stream>>>(xb, wt, bq, bk, bv, qb, kb, vb);
  k_attn<<<4096, 256, 0, stream>>>(qb, kb, vb, ao);
  k_out<<<2048, 256, 0, stream>>>(ao, wt + 1536 * KD, bo, out);
}

// Round 12
// 295.186 us; speedup vs baseline: 1.1207x; 1.0420x over previous
//
#include <hip/hip_runtime.h>

typedef _Float16 f16;
typedef _Float16 half8 __attribute__((ext_vector_type(8)));
typedef _Float16 half4 __attribute__((ext_vector_type(4)));
typedef float f32x4 __attribute__((ext_vector_type(4)));

#define B_SZ 512
#define NQ   128
#define CH   512
#define NH   8
#define DH   64
#define MTOK (B_SZ*NQ)   // 65536 tokens
#define KD   512

#define MFMA16(a,b,c) __builtin_amdgcn_mfma_f32_16x16x32_f16((a),(b),(c),0,0,0)

// global -> LDS direct DMA, 16B per lane. LDS dest is wave-uniform base + lane*16.
#define GLDS16(g,l) __builtin_amdgcn_global_load_lds( \
    (__attribute__((address_space(1))) void*)(g), \
    (__attribute__((address_space(3))) void*)(l), 16, 0, 0)

// ---------------- kernel 0: x fp32->fp16  +  W^T fp32->fp16, one launch ----------------
__global__ __launch_bounds__(256) void k_prep(
    const float* __restrict__ x,
    const float* __restrict__ Wq, const float* __restrict__ Wk,
    const float* __restrict__ Wv, const float* __restrict__ Wo,
    f16* __restrict__ xb, f16* __restrict__ wt) {
  const int bid = blockIdx.x;
  if (bid < 512) {
    for (int e = threadIdx.x; e < 2048; e += 256) {
      const int n = bid * 4 + (e >> 9);
      const int k = e & 511;
      const float* W = (n < 512) ? Wq : (n < 1024) ? Wk : (n < 1536) ? Wv : Wo;
      wt[n * 512 + k] = (f16)W[k * 512 + (n & 511)];
    }
  } else {
    const int n8 = MTOK * KD / 8;
    int i = (bid - 512) * 256 + threadIdx.x;
    const int stride = 2048 * 256;
    for (; i < n8; i += stride) {
      f32x4 a = ((const f32x4*)x)[2 * i];
      f32x4 b = ((const f32x4*)x)[2 * i + 1];
      half8 h;
      h[0] = (f16)a[0]; h[1] = (f16)a[1]; h[2] = (f16)a[2]; h[3] = (f16)a[3];
      h[4] = (f16)b[0]; h[5] = (f16)b[1]; h[6] = (f16)b[2]; h[7] = (f16)b[3];
      ((half8*)xb)[i] = h;
    }
  }
}

// ========== 128x128 GEMM core, BK=64, single-buffer m97-style (8 K-steps) ==========
// LDS tiles [128][64] f16 (16 KB each, 32 KB total). 128B row stride would be a
// 16-way bank conflict -> XOR swizzle: LDS (row, slot) holds global (row,
// slot ^ (row&7)), slot = 16B chunk. Pre-swizzled global SOURCE (GLDS dest linear,
// m104) + swizzled ds_read. Round trip verified: s_read ^ (row&7) = s_want;
// 8 distinct slots across ln&7 -> 2-way banks (free).
__device__ __forceinline__ void gemm128_bk64(
    const f16* __restrict__ gA,   // per-thread staging addr (pre-swizzled source)
    const f16* __restrict__ gB,
    f16* la, f16* lb, f32x4 (&acc)[4][4]) {
  const int tid = threadIdx.x;
  const int w = tid >> 6, lane = tid & 63;
  const int ln = lane & 15, g = lane >> 4;
  const int wr = w >> 1, wc = w & 1;

  const int ldst = w * 512;                 // + i*2048 per issue (elements)
  const int roA0 = (wr * 64 + ln) * 64;
  const int roB0 = (wc * 64 + ln) * 64;
  const int sx0 = ((0 * 4 + g) ^ (ln & 7)) * 8;   // ks = 0 slot (lane-const)
  const int sx1 = ((1 * 4 + g) ^ (ln & 7)) * 8;   // ks = 1 slot

#pragma unroll 1
  for (int kt = 0; kt < 8; ++kt) {
    const int k0 = kt * 64;
#pragma unroll
    for (int i = 0; i < 4; ++i) {
      GLDS16(gA + i * 32 * KD + k0, la + i * 2048 + ldst);
      GLDS16(gB + i * 32 * KD + k0, lb + i * 2048 + ldst);
    }
    __syncthreads();   // compiler drains vmcnt before s_barrier
    half8 af[4], bf[4];
#pragma unroll
    for (int ks = 0; ks < 2; ++ks) {
      const int sx = ks ? sx1 : sx0;
#pragma unroll
      for (int m = 0; m < 4; ++m)
        af[m] = *(const half8*)(la + roA0 + m * 1024 + sx);
#pragma unroll
      for (int n = 0; n < 4; ++n)
        bf[n] = *(const half8*)(lb + roB0 + n * 1024 + sx);
      __builtin_amdgcn_s_setprio(1);
#pragma unroll
      for (int m = 0; m < 4; ++m)
#pragma unroll
        for (int n = 0; n < 4; ++n)
          acc[m][n] = MFMA16(af[m], bf[n], acc[m][n]);
      __builtin_amdgcn_s_setprio(0);
    }
    __syncthreads();
  }
}

// staging source address for this thread (add tile-row base yourself):
//   row = w*8 + (lane>>3), slot = ((lane&7) ^ (lane>>3))*8
__device__ __forceinline__ int stage_src_off() {
  const int lane = threadIdx.x & 63, w = threadIdx.x >> 6;
  return (w * 8 + (lane >> 3)) * KD + (((lane & 7) ^ (lane >> 3)) << 3);
}

// ---------------- kernel 1: fused QKV projection GEMM ----------------
// XCD mapping: xcd = bid&7 owns mtiles [xcd*64, xcd*64+64); the 12 ntile-blocks of an
// mtile run on one XCD -> A panel fetched once into that XCD's L2.
__global__ __launch_bounds__(256, 4) void k_qkv(
    const f16* __restrict__ A, const f16* __restrict__ Bw,
    const float* __restrict__ bq, const float* __restrict__ bk,
    const float* __restrict__ bv,
    f16* __restrict__ qb, f16* __restrict__ kb, f16* __restrict__ vb) {
  __shared__ f16 la[128 * 64];
  __shared__ f16 lb[128 * 64];
  const int tid = threadIdx.x;
  const int w = tid >> 6, lane = tid & 63;
  const int ln = lane & 15, g = lane >> 4;
  const int wr = w >> 1, wc = w & 1;
  const int s = blockIdx.x >> 3;
  const int ml = s / 12;
  const int ntile = s - ml * 12;
  const int mtile = (blockIdx.x & 7) * 64 + ml;

  const int so = stage_src_off();
  const f16* gA = A + mtile * 128 * KD + so;
  const f16* gB = Bw + ntile * 128 * KD + so;

  f32x4 acc[4][4] = {};
  gemm128_bk64(gA, gB, la, lb, acc);

  const int b = mtile;  // 128 rows per tile == one batch
  const int colbase = ntile * 128 + wc * 64;
#pragma unroll
  for (int m = 0; m < 4; ++m) {
    const int nn0 = wr * 64 + m * 16 + g * 4;  // token row in batch (reg 0)
#pragma unroll
    for (int n = 0; n < 4; ++n) {
      const int col = colbase + n * 16 + ln;
      const int which = col >> 9;      // 0=Q 1=K 2=V (uniform per n)
      const int c = col & 511;
      const int h = c >> 6, d = c & 63;
      const float bias = (which == 0) ? bq[c] : (which == 1) ? bk[c] : bv[c];
      if (which < 2) {
        f16* dst = ((which == 0) ? qb : kb) + ((b * NH + h) * NQ + nn0) * DH + d;
#pragma unroll
        for (int r = 0; r < 4; ++r)
          dst[r * DH] = (f16)(acc[m][n][r] + bias);
      } else {
        half4 v4;
#pragma unroll
        for (int r = 0; r < 4; ++r)
          v4[r] = (f16)(acc[m][n][r] + bias);
        *(half4*)(vb + ((b * NH + h) * DH + d) * NQ + nn0) = v4;  // V^T
      }
    }
  }
}

// ---------------- kernel 2: causal attention, one block per (b,h) ----------------
__global__ __launch_bounds__(256, 2) void k_attn(
    const f16* __restrict__ qbuf, const f16* __restrict__ kbuf,
    const f16* __restrict__ vbuf, f16* __restrict__ ao) {
  __shared__ f16 kl[128 * 72];   // K [key][d], padded stride 72
  __shared__ f16 vl[64 * 136];   // V^T [d][key], padded stride 136
  __shared__ f16 pl[128 * 136];  // P [q][key], padded stride 136; later O bounce
  const int bh = blockIdx.x;
  const f16* Qp = qbuf + bh * (NQ * DH);
  const f16* Kp = kbuf + bh * (NQ * DH);
  const f16* Vp = vbuf + bh * (DH * NQ);
  const int tid = threadIdx.x;
  const int w = tid >> 6, lane = tid & 63;
  const int ln = lane & 15, g = lane >> 4;

#pragma unroll
  for (int i = 0; i < 4; ++i) {
    const int e = i * 2048 + tid * 8;
    *(half8*)(kl + (e >> 6) * 72 + (e & 63)) = *(const half8*)(Kp + e);
  }
#pragma unroll
  for (int i = 0; i < 4; ++i) {
    const int e = i * 2048 + tid * 8;
    *(half8*)(vl + (e >> 7) * 136 + (e & 127)) = *(const half8*)(Vp + e);
  }
  half8 qf[2][2];
#pragma unroll
  for (int m = 0; m < 2; ++m)
#pragma unroll
    for (int ks = 0; ks < 2; ++ks)
      qf[m][ks] = *(const half8*)(Qp + (w * 32 + m * 16 + ln) * DH + ks * 32 + g * 8);
  __syncthreads();

  f32x4 s[2][8] = {};
#pragma unroll
  for (int ks = 0; ks < 2; ++ks)
#pragma unroll
    for (int n = 0; n < 8; ++n) {
      half8 kf = *(const half8*)(kl + (n * 16 + ln) * 72 + ks * 32 + g * 8);
      s[0][n] = MFMA16(qf[0][ks], kf, s[0][n]);
      s[1][n] = MFMA16(qf[1][ks], kf, s[1][n]);
    }

  float inv[2][4];
#pragma unroll
  for (int m = 0; m < 2; ++m) {
#pragma unroll
    for (int r = 0; r < 4; ++r) {
      const int q = w * 32 + m * 16 + g * 4 + r;
      float z[8];
      float rm = -1e30f;
#pragma unroll
      for (int n = 0; n < 8; ++n) {
        const int col = n * 16 + ln;
        float zz = s[m][n][r] * 0.125f + ((col > q) ? -12500.0f : 0.0f);
        z[n] = zz;
        rm = fmaxf(rm, zz);
      }
      rm = fmaxf(rm, __shfl_xor(rm, 1));
      rm = fmaxf(rm, __shfl_xor(rm, 2));
      rm = fmaxf(rm, __shfl_xor(rm, 4));
      rm = fmaxf(rm, __shfl_xor(rm, 8));
      float rs = 0.f;
#pragma unroll
      for (int n = 0; n < 8; ++n) {
        const float p = __expf(z[n] - rm);   // masked cols -> exact 0
        rs += p;
        pl[q * 136 + n * 16 + ln] = (f16)p;  // unnormalized P
      }
      rs += __shfl_xor(rs, 1);
      rs += __shfl_xor(rs, 2);
      rs += __shfl_xor(rs, 4);
      rs += __shfl_xor(rs, 8);
      inv[m][r] = 1.0f / rs;
    }
  }

  f32x4 o[2][4] = {};
#pragma unroll
  for (int ks = 0; ks < 4; ++ks) {
    half8 pf0 = *(const half8*)(pl + (w * 32 + ln) * 136 + ks * 32 + g * 8);
    half8 pf1 = *(const half8*)(pl + (w * 32 + 16 + ln) * 136 + ks * 32 + g * 8);
#pragma unroll
    for (int n = 0; n < 4; ++n) {
      half8 vf = *(const half8*)(vl + (n * 16 + ln) * 136 + ks * 32 + g * 8);
      o[0][n] = MFMA16(pf0, vf, o[0][n]);
      o[1][n] = MFMA16(pf1, vf, o[1][n]);
    }
  }

  // O -> pl bounce (pl dead after PV), then coalesced 128B half8 stores
  __syncthreads();
#pragma unroll
  for (int m = 0; m < 2; ++m)
#pragma unroll
    for (int n = 0; n < 4; ++n)
#pragma unroll
      for (int r = 0; r < 4; ++r)
        pl[(w * 32 + m * 16 + g * 4 + r) * 136 + n * 16 + ln] =
            (f16)(o[m][n][r] * inv[m][r]);
  __syncthreads();
  const int b = bh >> 3, h = bh & 7;
  f16* dst = ao + (size_t)(b * NQ) * CH + h * DH;
  const int lr = lane >> 3, lc = lane & 7;   // 8 rows x (8 lanes of 16B)
#pragma unroll
  for (int p = 0; p < 4; ++p) {
    const int q = w * 32 + p * 8 + lr;
    half8 v = *(const half8*)(pl + q * 136 + lc * 8);
    *(half8*)(dst + (size_t)q * CH + lc * 8) = v;
  }
}

// ---------------- kernel 3: output projection GEMM (BK=64 core) ----------------
__global__ __launch_bounds__(256, 4) void k_out(
    const f16* __restrict__ A, const f16* __restrict__ Bw,
    const float* __restrict__ bo, float* __restrict__ out) {
  __shared__ f16 la[128 * 64];
  __shared__ f16 lb[128 * 64];
  const int tid = threadIdx.x;
  const int w = tid >> 6, lane = tid & 63;
  const int ln = lane & 15, g = lane >> 4;
  const int wr = w >> 1, wc = w & 1;
  const int s = blockIdx.x >> 3;
  const int ml = s >> 2;
  const int ntile = s & 3;
  const int mtile = (blockIdx.x & 7) * 64 + ml;

  const int so = stage_src_off();
  const f16* gA = A + mtile * 128 * KD + so;
  const f16* gB = Bw + ntile * 128 * KD + so;

  f32x4 acc[4][4] = {};
  gemm128_bk64(gA, gB, la, lb, acc);

  const int colbase = ntile * 128 + wc * 64;
#pragma unroll
  for (int m = 0; m < 4; ++m) {
    const int tok0 = mtile * 128 + wr * 64 + m * 16 + g * 4;
#pragma unroll
    for (int n = 0; n < 4; ++n) {
      const int col = colbase + n * 16 + ln;
      const float bias = bo[col];
      float* dst = out + (size_t)tok0 * CH + col;
#pragma unroll
      for (int r = 0; r < 4; ++r)
        dst[r * CH] = acc[m][n][r] + bias;
    }
  }
}

extern "C" void kernel_launch(void* const* d_in, const int* in_sizes, int n_in,
                              void* d_out, int out_size, void* d_ws, size_t ws_size,
                              hipStream_t stream) {
  (void)in_sizes; (void)n_in; (void)out_size; (void)ws_size;
  const float* x  = (const float*)d_in[0];
  const float* Wq = (const float*)d_in[1];
  const float* bq = (const float*)d_in[2];
  const float* Wk = (const float*)d_in[3];
  const float* bk = (const float*)d_in[4];
  const float* Wv = (const float*)d_in[5];
  const float* bv = (const float*)d_in[6];
  const float* Wo = (const float*)d_in[7];
  const float* bo = (const float*)d_in[8];
  float* out = (float*)d_out;

  char* ws = (char*)d_ws;
  const size_t SZ = (size_t)MTOK * KD * sizeof(f16);  // 64 MB
  f16* xb = (f16*)(ws);                // x in fp16
  f16* qb = (f16*)(ws + SZ);           // Q [b][h][n][d]
  f16* kb = (f16*)(ws + 2 * SZ);       // K [b][h][n][d]
  f16* vb = (f16*)(ws + 3 * SZ);       // V^T [b][h][d][n]
  f16* wt = (f16*)(ws + 4 * SZ);       // W^T fp16, 2048x512
  f16* ao = xb;                        // attn out aliases xb (xb dead by then)

  k_prep<<<2560, 256, 0, stream>>>(x, Wq, Wk, Wv, Wo, xb, wt);
  k_qkv<<<6144, 256, 0, stream>>>(xb, wt, bq, bk, bv, qb, kb, vb);
  k_attn<<<4096, 256, 0, stream>>>(qb, kb, vb, ao);
  k_out<<<2048, 256, 0, stream>>>(ao, wt + 1536 * KD, bo, out);
}